// Round 1
// baseline (363.179 us; speedup 1.0000x reference)
//
#include <hip/hip_runtime.h>
#include <math.h>

#define CH_EPS 1e-6f
#define CH_N 4096
#define CH_D 3

// One thread owns one point of the "own" set; scans all points of the "other"
// set (wave-uniform addresses -> scalar loads), tracking min squared distance.
// dir 0: own=y, other=x  (min over j of ||y_i - x_j||)   [ref min2]
// dir 1: own=x, other=y  (min over i of ||y_i - x_j||)   [ref min1]
__global__ __launch_bounds__(256) void chamfer_min_kernel(
    const float* __restrict__ x, const float* __restrict__ y,
    float* __restrict__ out) {
    const int tid = threadIdx.x;
    const int i   = blockIdx.x * 256 + tid;
    const int b   = blockIdx.y;
    const int dir = blockIdx.z;

    const float* own   = (dir == 0) ? y : x;
    const float* other = (dir == 0) ? x : y;

    const float* op = own + ((size_t)b * CH_N + i) * CH_D;
    const float px = op[0];
    const float py = op[1];
    const float pz = op[2];

    const float* __restrict__ q = other + (size_t)b * CH_N * CH_D;

    float m = 3.4e38f;
#pragma unroll 8
    for (int j = 0; j < CH_N; ++j) {
        const float qx = q[j * 3 + 0];
        const float qy = q[j * 3 + 1];
        const float qz = q[j * 3 + 2];
        const float dx = qx - px;
        const float dy = qy - py;
        const float dz = qz - pz;
        float d2 = dx * dx;
        d2 = fmaf(dy, dy, d2);
        d2 = fmaf(dz, dz, d2);
        m = fminf(m, d2);
    }

    // per-point contribution to the mean
    float v = sqrtf(CH_EPS + m) * (1.0f / (float)CH_N);

    // wave64 shuffle reduce
#pragma unroll
    for (int off = 32; off > 0; off >>= 1) v += __shfl_down(v, off, 64);

    __shared__ float wsum[4];
    if ((tid & 63) == 0) wsum[tid >> 6] = v;
    __syncthreads();
    if (tid == 0) {
        const float s = wsum[0] + wsum[1] + wsum[2] + wsum[3];
        atomicAdd(out + b, s);
    }
}

extern "C" void kernel_launch(void* const* d_in, const int* in_sizes, int n_in,
                              void* d_out, int out_size, void* d_ws, size_t ws_size,
                              hipStream_t stream) {
    const float* x = (const float*)d_in[0];
    const float* y = (const float*)d_in[1];
    float* out = (float*)d_out;

    // out is poisoned; we accumulate into it, so zero it first (capture-safe).
    hipMemsetAsync(out, 0, (size_t)out_size * sizeof(float), stream);

    dim3 grid(CH_N / 256, 8, 2);
    dim3 block(256);
    chamfer_min_kernel<<<grid, block, 0, stream>>>(x, y, out);
}

// Round 2
// 59.422 us; speedup vs baseline: 6.1119x; 6.1119x over previous
//
#include <hip/hip_runtime.h>
#include <math.h>

#define CH_EPS   1e-6f
#define CH_N     4096
#define CH_BS    8
#define CH_JCH   512            // j-chunk per block
#define CH_NJC   (CH_N / CH_JCH)

// Phase 1: each thread owns one "own" point, scans a 512-point chunk of the
// "other" set (wave-uniform addresses -> scalar loads), keeps 8 independent
// min-d2 accumulators, then atomicMin's the d2 bit pattern into ws.
// For non-negative floats, unsigned compare == float compare.
__global__ __launch_bounds__(256) void chamfer_min_kernel(
    const float* __restrict__ x, const float* __restrict__ y,
    unsigned int* __restrict__ ws) {
    const int tid  = threadIdx.x;
    const int it   = blockIdx.x / CH_NJC;      // i-tile [0,16)
    const int jc   = blockIdx.x % CH_NJC;      // j-chunk [0,8)
    const int i    = it * 256 + tid;
    const int b    = blockIdx.y;
    const int dir  = blockIdx.z;

    const float* own   = (dir == 0) ? y : x;
    const float* other = (dir == 0) ? x : y;

    const float* op = own + ((size_t)b * CH_N + i) * 3;
    const float px = op[0];
    const float py = op[1];
    const float pz = op[2];

    const float* __restrict__ q = other + ((size_t)b * CH_N + (size_t)jc * CH_JCH) * 3;

    float mm[8];
#pragma unroll
    for (int k = 0; k < 8; ++k) mm[k] = 3.4e38f;

    for (int j0 = 0; j0 < CH_JCH; j0 += 8) {
#pragma unroll
        for (int k = 0; k < 8; ++k) {
            const float qx = q[(j0 + k) * 3 + 0];
            const float qy = q[(j0 + k) * 3 + 1];
            const float qz = q[(j0 + k) * 3 + 2];
            const float dx = qx - px;
            const float dy = qy - py;
            const float dz = qz - pz;
            float d2 = dx * dx;
            d2 = fmaf(dy, dy, d2);
            d2 = fmaf(dz, dz, d2);
            mm[k] = fminf(mm[k], d2);
        }
    }

    float m = fminf(fminf(fminf(mm[0], mm[1]), fminf(mm[2], mm[3])),
                    fminf(fminf(mm[4], mm[5]), fminf(mm[6], mm[7])));

    atomicMin(&ws[((size_t)dir * CH_BS + b) * CH_N + i], __float_as_uint(m));
}

// Phase 2: one block per batch; sum sqrt(eps+min)/N over both directions.
__global__ __launch_bounds__(256) void chamfer_finalize_kernel(
    const unsigned int* __restrict__ ws, float* __restrict__ out) {
    const int b = blockIdx.x;
    const int tid = threadIdx.x;

    float s = 0.0f;
    for (int k = tid; k < 2 * CH_N; k += 256) {
        const int dir = k >> 12;          // /4096
        const int i   = k & (CH_N - 1);
        const float d2 = __uint_as_float(ws[((size_t)dir * CH_BS + b) * CH_N + i]);
        s += sqrtf(CH_EPS + d2);
    }
    s *= (1.0f / (float)CH_N);

#pragma unroll
    for (int off = 32; off > 0; off >>= 1) s += __shfl_down(s, off, 64);

    __shared__ float wsum[4];
    if ((tid & 63) == 0) wsum[tid >> 6] = s;
    __syncthreads();
    if (tid == 0) out[b] = wsum[0] + wsum[1] + wsum[2] + wsum[3];
}

extern "C" void kernel_launch(void* const* d_in, const int* in_sizes, int n_in,
                              void* d_out, int out_size, void* d_ws, size_t ws_size,
                              hipStream_t stream) {
    const float* x = (const float*)d_in[0];
    const float* y = (const float*)d_in[1];
    float* out = (float*)d_out;
    unsigned int* ws = (unsigned int*)d_ws;   // 2*8*4096 uints = 256 KiB

    // init partial-min slots to +inf (0xFFFFFFFF compares as max unsigned)
    hipMemsetAsync(ws, 0xFF, (size_t)2 * CH_BS * CH_N * sizeof(unsigned int), stream);

    dim3 grid1((CH_N / 256) * CH_NJC, CH_BS, 2);
    chamfer_min_kernel<<<grid1, dim3(256), 0, stream>>>(x, y, ws);

    chamfer_finalize_kernel<<<dim3(CH_BS), dim3(256), 0, stream>>>(ws, out);
}